// Round 5
// baseline (293.981 us; speedup 1.0000x reference)
//
#include <hip/hip_runtime.h>
#include <math.h>

#define HW 9216          // 96*96
#define WID 96
#define CIN 256
#define COUT 256
#define NTOT 18432       // B*HW
#define KC 2304          // CIN*9  (K of the implicit GEMM)
#define KSPLIT 4
#define KPER 576         // KC / KSPLIT
#define KSTEPS 18        // KPER / 32

typedef short bf16x8 __attribute__((ext_vector_type(8)));
typedef float f32x4  __attribute__((ext_vector_type(4)));

#define GLOAD_LDS16(g, l)                                              \
    __builtin_amdgcn_global_load_lds(                                  \
        (const __attribute__((address_space(1))) void*)(g),            \
        (__attribute__((address_space(3))) void*)(l), 16, 0, 0)

__device__ __forceinline__ unsigned short f2bf(float f) {
    union { float f; unsigned int u; } v; v.f = f;
    unsigned int u = v.u;
    return (unsigned short)((u + 0x7fffu + ((u >> 16) & 1u)) >> 16);  // RNE
}

// ws layout (float offsets) — wb is 589824 USHORTS = 294912 float slots:
//   off   : 0       .. 331776
//   stats : 331776  .. 331904
//   wb    : 331904  .. 626816   (256x2304 ushort, wb[oc][k*256+c])
//   xt    : 626816  .. 5345408  (NHWC fp32)
//   P     : 5345408 ..          (Nc x 2304 ushort, chunked)

// One prologue kernel, branched by block range:
//  [0,4608): xt transpose | [4608,6912): wb bf16 | [6912,8208): off init + stats
//  [8208,12816): out zero
__global__ __launch_bounds__(256) void prelude(const float* __restrict__ x,
                                               float* __restrict__ xt,
                                               const float* __restrict__ cw,
                                               unsigned short* __restrict__ wb,
                                               const float* __restrict__ offset_b,
                                               float* __restrict__ off,
                                               float* __restrict__ stats,
                                               float* __restrict__ out) {
    __shared__ float L[32][33];
    int blk = blockIdx.x, t = threadIdx.x;
    if (blk < 4608) {                       // x NCHW -> NHWC
        int pt = blk % 288, ct = (blk / 288) & 7, b = blk / 2304;
        int pl = t & 31, ch = t >> 5;
#pragma unroll
        for (int i = 0; i < 4; i++) {
            int cl = ch * 4 + i;
            L[cl][pl] = x[((size_t)(b * CIN + ct * 32 + cl)) * HW + pt * 32 + pl];
        }
        __syncthreads();
        int cc = t & 31;
#pragma unroll
        for (int i = 0; i < 4; i++) {
            int pr = ch * 4 + i;
            xt[((size_t)(b * HW + pt * 32 + pr)) * 256 + ct * 32 + cc] = L[cc][pr];
        }
    } else if (blk < 6912) {                // conv_w -> wb bf16 [oc][k*256+c]
        int i = (blk - 4608) * 256 + t;
        int oc = i / KC, kc = i % KC;
        int k = kc >> 8, c = kc & 255;
        wb[i] = f2bf(cw[(oc * CIN + c) * 9 + k]);
    } else if (blk < 8208) {                // off = bias, stats = 0
        int i = (blk - 6912) * 256 + t;
        if (i < 331776) off[i] = offset_b[(i / HW) % 18];
        if (i < 128) stats[i] = 0.f;
    } else {                                // out = 0 (split-K accumulates)
        int i4 = (blk - 8208) * 256 + t;
        ((float4*)out)[i4] = make_float4(0.f, 0.f, 0.f, 0.f);
    }
}

// 3x3 pad-1 conv -> 18 offset channels. 16 c-chunks x 72 = 1152 blocks.
__global__ __launch_bounds__(256) void offset_conv(const float* __restrict__ x,
                                                   const float* __restrict__ ow,
                                                   float* __restrict__ off) {
    int chunk = blockIdx.x / 72;
    int pg = (blockIdx.x % 72) * 256 + threadIdx.x;
    int b  = pg / HW;
    int p  = pg % HW;
    int ho = p / WID, wo = p % WID;
    const float* xb = x + (size_t)b * CIN * HW;

    float acc[18];
#pragma unroll
    for (int ch = 0; ch < 18; ch++) acc[ch] = 0.f;

    int c0 = chunk * 16;
    for (int ci = 0; ci < 16; ci++) {
        int c = c0 + ci;
        const float* xc = xb + (size_t)c * HW;
#pragma unroll
        for (int ky = 0; ky < 3; ky++) {
            int y = ho - 1 + ky;
            if (y < 0 || y >= 96) continue;
#pragma unroll
            for (int kx = 0; kx < 3; kx++) {
                int xx = wo - 1 + kx;
                float xv = (xx >= 0 && xx < 96) ? xc[y * WID + xx] : 0.f;
                int widx = c * 9 + ky * 3 + kx;
#pragma unroll
                for (int ch = 0; ch < 18; ch++)
                    acc[ch] += xv * ow[ch * (CIN * 9) + widx];
            }
        }
    }
#pragma unroll
    for (int ch = 0; ch < 18; ch++)
        atomicAdd(&off[((size_t)b * 18 + ch) * HW + p], acc[ch]);
}

// Fused meta + bilinear gather. One wave per (n,k); all lanes compute the
// same meta (broadcast loads), then 4 coalesced 1KB corner-row reads (NHWC).
__global__ __launch_bounds__(256) void gather3(const float* __restrict__ xt,
                                               const float* __restrict__ off,
                                               unsigned short* __restrict__ P,
                                               int n0) {
    int t    = threadIdx.x;
    int k    = blockIdx.x;          // 0..8
    int wave = t >> 6;
    int lane = t & 63;
    int nl   = blockIdx.y * 4 + wave;
    int n    = n0 + nl;
    int b    = n / HW, p = n % HW;
    int ho   = p / WID, wo = p % WID;
    int ky   = k / 3, kx = k % 3;

    float dy = off[((size_t)b * 18 + 2 * k)     * HW + p];
    float dx = off[((size_t)b * 18 + 2 * k + 1) * HW + p];
    float sy = (float)(ho - 1 + ky) + dy;
    float sx = (float)(wo - 1 + kx) + dx;
    float y0f = floorf(sy), x0f = floorf(sx);
    float fy = sy - y0f, fx = sx - x0f;
    int y0 = (int)y0f, x0 = (int)x0f;
    int y1 = y0 + 1, x1 = x0 + 1;
    float vy0 = (y0 >= 0 && y0 < 96) ? 1.f : 0.f;
    float vy1 = (y1 >= 0 && y1 < 96) ? 1.f : 0.f;
    float vx0 = (x0 >= 0 && x0 < 96) ? 1.f : 0.f;
    float vx1 = (x1 >= 0 && x1 < 96) ? 1.f : 0.f;
    int iy0 = min(max(y0, 0), 95) * WID, iy1 = min(max(y1, 0), 95) * WID;
    int ix0 = min(max(x0, 0), 95),       ix1 = min(max(x1, 0), 95);
    float w0 = (1.f - fy) * (1.f - fx) * vy0 * vx0;
    float w1 = (1.f - fy) * fx         * vy0 * vx1;
    float w2 = fy         * (1.f - fx) * vy1 * vx0;
    float w3 = fy         * fx         * vy1 * vx1;

    const float* xb = xt + (size_t)b * (HW * 256);
    int c4 = lane * 4;
    float4 v0 = *(const float4*)(xb + (size_t)(iy0 + ix0) * 256 + c4);
    float4 v1 = *(const float4*)(xb + (size_t)(iy0 + ix1) * 256 + c4);
    float4 v2 = *(const float4*)(xb + (size_t)(iy1 + ix0) * 256 + c4);
    float4 v3 = *(const float4*)(xb + (size_t)(iy1 + ix1) * 256 + c4);
    float r0 = w0 * v0.x + w1 * v1.x + w2 * v2.x + w3 * v3.x;
    float r1 = w0 * v0.y + w1 * v1.y + w2 * v2.y + w3 * v3.y;
    float r2 = w0 * v0.z + w1 * v1.z + w2 * v2.z + w3 * v3.z;
    float r3 = w0 * v0.w + w1 * v1.w + w2 * v2.w + w3 * v3.w;
    uint2 o;
    o.x = (unsigned)f2bf(r0) | ((unsigned)f2bf(r1) << 16);
    o.y = (unsigned)f2bf(r2) | ((unsigned)f2bf(r3) << 16);
    *((uint2*)(P + (size_t)nl * KC + k * 256 + c4)) = o;
}

// Split-K bf16 MFMA GEMM. Block tile 128M x 128N x 576K; 4 waves, each 64x64
// (4x4 16x16x32 tiles). LDS in MFMA-fragment order via global_load_lds
// width=16 (dest = base + lane*16 == fragment read order -> conflict-free
// ds_read_b128). Flat grid, XCD swizzle: blocks sharing a B-tile are 8 apart.
__global__ __launch_bounds__(256) void gemm_mfma(const unsigned short* __restrict__ wb,
                                                 const unsigned short* __restrict__ P,
                                                 float* __restrict__ out,
                                                 int n0, int nbn) {
    __shared__ __align__(16) unsigned short As[4096];   // 8 frags x 64 lanes x 16B
    __shared__ __align__(16) unsigned short Bs[4096];
    int t    = threadIdx.x;
    int wave = t >> 6;
    int lane = t & 63;
    int l15  = lane & 15, quad = lane >> 4;

    int f   = blockIdx.x;
    int m   = (f >> 3) & 1;
    int nks = (f & 7) + ((f >> 4) << 3);
    int nb  = nks % nbn;
    int ks  = nks / nbn;
    int m0  = m * 128;
    int kc0 = ks * KPER;
    int wm  = wave >> 1, wn = wave & 1;

    f32x4 acc[4][4];
#pragma unroll
    for (int i = 0; i < 4; i++)
#pragma unroll
        for (int j = 0; j < 4; j++) acc[i][j] = (f32x4)0.f;

    const unsigned short* Ag0 = wb + (size_t)(m0 + wave * 16 + l15) * KC + kc0 + quad * 8;
    const unsigned short* Bg0 = P  + (size_t)(nb * 128 + wave * 16 + l15) * KC + kc0 + quad * 8;

#pragma unroll 2
    for (int step = 0; step < KSTEPS; step++) {
        __syncthreads();
        int kof = step * 32;
#pragma unroll
        for (int h = 0; h < 2; h++) {   // wave stages A frags {w, w+4}, B frags {w, w+4}
            int fa = wave + h * 4;
            GLOAD_LDS16(Ag0 + (size_t)(h * 64) * KC + kof, &As[fa * 512]);
            GLOAD_LDS16(Bg0 + (size_t)(h * 64) * KC + kof, &Bs[fa * 512]);
        }
        __syncthreads();
        bf16x8 a[4], b[4];
#pragma unroll
        for (int i = 0; i < 4; i++)
            a[i] = *(const bf16x8*)&As[(wm * 4 + i) * 512 + lane * 8];
#pragma unroll
        for (int j = 0; j < 4; j++)
            b[j] = *(const bf16x8*)&Bs[(wn * 4 + j) * 512 + lane * 8];
#pragma unroll
        for (int i = 0; i < 4; i++)
#pragma unroll
            for (int j = 0; j < 4; j++)
                acc[i][j] = __builtin_amdgcn_mfma_f32_16x16x32_bf16(a[i], b[j], acc[i][j], 0, 0, 0);
    }

    int nbase = n0 + nb * 128 + wn * 64;
#pragma unroll
    for (int i = 0; i < 4; i++) {
#pragma unroll
        for (int j = 0; j < 4; j++) {
            int n  = nbase + j * 16 + l15;
            int b_ = n / HW, p = n % HW;
            int mr = m0 + wm * 64 + i * 16 + quad * 4;
            float* ob = out + (size_t)b_ * COUT * HW + (size_t)mr * HW + p;
#pragma unroll
            for (int r = 0; r < 4; r++)
                atomicAdd(ob + (size_t)r * HW, acc[i][j][r]);
        }
    }
}

// Partial GN stats: 512 blocks, atomics into stats (zeroed in prelude).
__global__ __launch_bounds__(256) void gn_stats(const float* __restrict__ out,
                                                float* __restrict__ stats) {
    __shared__ float sdata[512];
    int blk = blockIdx.x;
    int bg  = blk >> 3;
    const float4* b4 = (const float4*)(out + (size_t)bg * 73728 + (size_t)(blk & 7) * 9216);
    float s = 0.f, ss = 0.f;
    for (int i = threadIdx.x; i < 2304; i += 256) {
        float4 v = b4[i];
        s  += v.x + v.y + v.z + v.w;
        ss += v.x * v.x + v.y * v.y + v.z * v.z + v.w * v.w;
    }
    sdata[threadIdx.x]       = s;
    sdata[256 + threadIdx.x] = ss;
    __syncthreads();
    for (int st = 128; st > 0; st >>= 1) {
        if (threadIdx.x < st) {
            sdata[threadIdx.x]       += sdata[threadIdx.x + st];
            sdata[256 + threadIdx.x] += sdata[256 + threadIdx.x + st];
        }
        __syncthreads();
    }
    if (threadIdx.x == 0) {
        atomicAdd(&stats[bg * 2],     sdata[0]);
        atomicAdd(&stats[bg * 2 + 1], sdata[256]);
    }
}

__global__ __launch_bounds__(256) void gn_norm(float* __restrict__ out,
                                               const float* __restrict__ stats,
                                               const float* __restrict__ gamma,
                                               const float* __restrict__ beta) {
    int i4 = blockIdx.x * 256 + threadIdx.x;
    if (i4 >= 1179648) return;
    float4 v = ((const float4*)out)[i4];
    int e  = i4 * 4;
    int ch = (e / HW) & 255;
    int b  = e / (HW * 256);
    int bg = b * 32 + (ch >> 3);
    float s = stats[bg * 2], ss = stats[bg * 2 + 1];
    float mean = s * (1.f / 73728.f);
    float rs   = rsqrtf(ss * (1.f / 73728.f) - mean * mean + 1e-5f);
    float ga = gamma[ch] * rs;
    float be = beta[ch] - mean * ga;
    v.x = fmaxf(v.x * ga + be, 0.f);
    v.y = fmaxf(v.y * ga + be, 0.f);
    v.z = fmaxf(v.z * ga + be, 0.f);
    v.w = fmaxf(v.w * ga + be, 0.f);
    ((float4*)out)[i4] = v;
}

extern "C" void kernel_launch(void* const* d_in, const int* in_sizes, int n_in,
                              void* d_out, int out_size, void* d_ws, size_t ws_size,
                              hipStream_t stream) {
    const float* x        = (const float*)d_in[0];
    const float* offset_w = (const float*)d_in[1];
    const float* offset_b = (const float*)d_in[2];
    const float* conv_w   = (const float*)d_in[3];
    const float* gamma    = (const float*)d_in[4];
    const float* beta     = (const float*)d_in[5];
    float* out = (float*)d_out;
    float* ws  = (float*)d_ws;

    float*          off   = ws;
    float*          stats = ws + 331776;
    unsigned short* wb    = (unsigned short*)(ws + 331904);
    float*          xt    = ws + 626816;    // FIX: wb is 294912 float slots, not 147456
    unsigned short* P     = (unsigned short*)(ws + 5345408);

    const size_t baseB = 5345408ull * 4ull;
    int Nc;
    if      (ws_size >= baseB + (size_t)18432 * KC * 2) Nc = 18432;
    else if (ws_size >= baseB + (size_t)9216  * KC * 2) Nc = 9216;
    else if (ws_size >= baseB + (size_t)4608  * KC * 2) Nc = 4608;
    else                                                Nc = 2304;

    hipLaunchKernelGGL(prelude,     dim3(12816), dim3(256), 0, stream,
                       x, xt, conv_w, wb, offset_b, off, stats, out);
    hipLaunchKernelGGL(offset_conv, dim3(1152),  dim3(256), 0, stream, x, offset_w, off);
    for (int n0 = 0; n0 < NTOT; n0 += Nc) {
        hipLaunchKernelGGL(gather3, dim3(9, Nc / 4), dim3(256), 0, stream, xt, off, P, n0);
        hipLaunchKernelGGL(gemm_mfma, dim3((Nc / 128) * 2 * KSPLIT), dim3(256), 0, stream,
                           wb, P, out, n0, Nc / 128);
    }
    hipLaunchKernelGGL(gn_stats, dim3(512),  dim3(256), 0, stream, out, stats);
    hipLaunchKernelGGL(gn_norm,  dim3(4608), dim3(256), 0, stream, out, stats, gamma, beta);
}

// Round 6
// 265.822 us; speedup vs baseline: 1.1059x; 1.1059x over previous
//
#include <hip/hip_runtime.h>
#include <math.h>

#define HW 9216          // 96*96
#define WID 96
#define CIN 256
#define COUT 256
#define NTOT 18432       // B*HW
#define KC 2304          // CIN*9  (K of the implicit GEMM)
#define KSTEPS 36        // KC / 64

typedef short bf16x8 __attribute__((ext_vector_type(8)));
typedef float f32x4  __attribute__((ext_vector_type(4)));

#define GLOAD_LDS16(g, l)                                              \
    __builtin_amdgcn_global_load_lds(                                  \
        (const __attribute__((address_space(1))) void*)(g),            \
        (__attribute__((address_space(3))) void*)(l), 16, 0, 0)

__device__ __forceinline__ unsigned short f2bf(float f) {
    union { float f; unsigned int u; } v; v.f = f;
    unsigned int u = v.u;
    return (unsigned short)((u + 0x7fffu + ((u >> 16) & 1u)) >> 16);  // RNE
}

// ws layout (float offsets) — wb is 589824 ushorts = 294912 float slots:
//   off   : 0       .. 331776
//   stats : 331776  .. 331904
//   wb    : 331904  .. 626816   (256x2304 ushort, wb[oc][k*256+c])
//   xt    : 626816  .. 5345408  (NHWC fp32)
//   P     : 5345408 ..          (Nc x 2304 ushort, chunked)

// Prologue: [0,4608) xt transpose | [4608,6912) wb bf16 | [6912,8208) off init + stats=0
__global__ __launch_bounds__(256) void prelude(const float* __restrict__ x,
                                               float* __restrict__ xt,
                                               const float* __restrict__ cw,
                                               unsigned short* __restrict__ wb,
                                               const float* __restrict__ offset_b,
                                               float* __restrict__ off,
                                               float* __restrict__ stats) {
    __shared__ float L[32][33];
    int blk = blockIdx.x, t = threadIdx.x;
    if (blk < 4608) {                       // x NCHW -> NHWC
        int pt = blk % 288, ct = (blk / 288) & 7, b = blk / 2304;
        int pl = t & 31, ch = t >> 5;
#pragma unroll
        for (int i = 0; i < 4; i++) {
            int cl = ch * 4 + i;
            L[cl][pl] = x[((size_t)(b * CIN + ct * 32 + cl)) * HW + pt * 32 + pl];
        }
        __syncthreads();
        int cc = t & 31;
#pragma unroll
        for (int i = 0; i < 4; i++) {
            int pr = ch * 4 + i;
            xt[((size_t)(b * HW + pt * 32 + pr)) * 256 + ct * 32 + cc] = L[cc][pr];
        }
    } else if (blk < 6912) {                // conv_w -> wb bf16 [oc][k*256+c]
        int i = (blk - 4608) * 256 + t;
        int oc = i / KC, kc = i % KC;
        int k = kc >> 8, c = kc & 255;
        wb[i] = f2bf(cw[(oc * CIN + c) * 9 + k]);
    } else {                                // off = bias, stats = 0
        int i = (blk - 6912) * 256 + t;
        if (i < 331776) off[i] = offset_b[(i / HW) % 18];
        if (i < 128) stats[i] = 0.f;
    }
}

// 3x3 pad-1 conv -> 18 offset channels. 16 c-chunks x 72 = 1152 blocks.
__global__ __launch_bounds__(256) void offset_conv(const float* __restrict__ x,
                                                   const float* __restrict__ ow,
                                                   float* __restrict__ off) {
    int chunk = blockIdx.x / 72;
    int pg = (blockIdx.x % 72) * 256 + threadIdx.x;
    int b  = pg / HW;
    int p  = pg % HW;
    int ho = p / WID, wo = p % WID;
    const float* xb = x + (size_t)b * CIN * HW;

    float acc[18];
#pragma unroll
    for (int ch = 0; ch < 18; ch++) acc[ch] = 0.f;

    int c0 = chunk * 16;
    for (int ci = 0; ci < 16; ci++) {
        int c = c0 + ci;
        const float* xc = xb + (size_t)c * HW;
#pragma unroll
        for (int ky = 0; ky < 3; ky++) {
            int y = ho - 1 + ky;
            if (y < 0 || y >= 96) continue;
#pragma unroll
            for (int kx = 0; kx < 3; kx++) {
                int xx = wo - 1 + kx;
                float xv = (xx >= 0 && xx < 96) ? xc[y * WID + xx] : 0.f;
                int widx = c * 9 + ky * 3 + kx;
#pragma unroll
                for (int ch = 0; ch < 18; ch++)
                    acc[ch] += xv * ow[ch * (CIN * 9) + widx];
            }
        }
    }
#pragma unroll
    for (int ch = 0; ch < 18; ch++)
        atomicAdd(&off[((size_t)b * 18 + ch) * HW + p], acc[ch]);
}

// Fused meta + bilinear gather. One wave per (n,k); 4 coalesced 1KB corner
// row reads from NHWC xt. P[n_local][k*256+c] bf16.
__global__ __launch_bounds__(256) void gather3(const float* __restrict__ xt,
                                               const float* __restrict__ off,
                                               unsigned short* __restrict__ P,
                                               int n0) {
    int t    = threadIdx.x;
    int k    = blockIdx.x;          // 0..8
    int wave = t >> 6;
    int lane = t & 63;
    int nl   = blockIdx.y * 4 + wave;
    int n    = n0 + nl;
    int b    = n / HW, p = n % HW;
    int ho   = p / WID, wo = p % WID;
    int ky   = k / 3, kx = k % 3;

    float dy = off[((size_t)b * 18 + 2 * k)     * HW + p];
    float dx = off[((size_t)b * 18 + 2 * k + 1) * HW + p];
    float sy = (float)(ho - 1 + ky) + dy;
    float sx = (float)(wo - 1 + kx) + dx;
    float y0f = floorf(sy), x0f = floorf(sx);
    float fy = sy - y0f, fx = sx - x0f;
    int y0 = (int)y0f, x0 = (int)x0f;
    int y1 = y0 + 1, x1 = x0 + 1;
    float vy0 = (y0 >= 0 && y0 < 96) ? 1.f : 0.f;
    float vy1 = (y1 >= 0 && y1 < 96) ? 1.f : 0.f;
    float vx0 = (x0 >= 0 && x0 < 96) ? 1.f : 0.f;
    float vx1 = (x1 >= 0 && x1 < 96) ? 1.f : 0.f;
    int iy0 = min(max(y0, 0), 95) * WID, iy1 = min(max(y1, 0), 95) * WID;
    int ix0 = min(max(x0, 0), 95),       ix1 = min(max(x1, 0), 95);
    float w0 = (1.f - fy) * (1.f - fx) * vy0 * vx0;
    float w1 = (1.f - fy) * fx         * vy0 * vx1;
    float w2 = fy         * (1.f - fx) * vy1 * vx0;
    float w3 = fy         * fx         * vy1 * vx1;

    const float* xb = xt + (size_t)b * (HW * 256);
    int c4 = lane * 4;
    float4 v0 = *(const float4*)(xb + (size_t)(iy0 + ix0) * 256 + c4);
    float4 v1 = *(const float4*)(xb + (size_t)(iy0 + ix1) * 256 + c4);
    float4 v2 = *(const float4*)(xb + (size_t)(iy1 + ix0) * 256 + c4);
    float4 v3 = *(const float4*)(xb + (size_t)(iy1 + ix1) * 256 + c4);
    float r0 = w0 * v0.x + w1 * v1.x + w2 * v2.x + w3 * v3.x;
    float r1 = w0 * v0.y + w1 * v1.y + w2 * v2.y + w3 * v3.y;
    float r2 = w0 * v0.z + w1 * v1.z + w2 * v2.z + w3 * v3.z;
    float r3 = w0 * v0.w + w1 * v1.w + w2 * v2.w + w3 * v3.w;
    uint2 o;
    o.x = (unsigned)f2bf(r0) | ((unsigned)f2bf(r1) << 16);
    o.y = (unsigned)f2bf(r2) | ((unsigned)f2bf(r3) << 16);
    *((uint2*)(P + (size_t)nl * KC + k * 256 + c4)) = o;
}

// No-split-K bf16 MFMA GEMM. Block = 2 waves (128 thr), tile 128M x 64N,
// wave tile 64x64 (4x4 16x16x32, best FLOP/LDS-byte). BK=64 per step
// (36 steps -> half the barrier drains). Fragment-order LDS via
// global_load_lds w=16 (conflict-free, proven R5). Plain stores + fused GN
// partial stats. Grid 2*nbn2 with XCD pairing (both m-blocks of an n-tile
// land on the same XCD: id%8 equal).
__global__ __launch_bounds__(128) void gemm_mfma(const unsigned short* __restrict__ wb,
                                                 const unsigned short* __restrict__ P,
                                                 float* __restrict__ out,
                                                 float* __restrict__ stats,
                                                 int n0, int nbn2) {
    __shared__ __align__(16) unsigned short As[16 * 512];  // [khalf*8 + frag][lane*8]
    __shared__ __align__(16) unsigned short Bs[8 * 512];
    __shared__ float sgrp[32];
    int t    = threadIdx.x;
    int w    = t >> 6;
    int lane = t & 63;
    int l15  = lane & 15, quad = lane >> 4;

    int f = blockIdx.x, g, mb;
    if ((nbn2 & 7) == 0) {          // XCD pairing swizzle
        int h = f & 15, r = f >> 4;
        mb = h >> 3;
        g  = r * 8 + (h & 7);
    } else {
        mb = f & 1; g = f >> 1;
    }
    int m0    = mb * 128;
    int ntile = n0 + g * 64;

    f32x4 acc[4][4];
#pragma unroll
    for (int i = 0; i < 4; i++)
#pragma unroll
        for (int j = 0; j < 4; j++) acc[i][j] = (f32x4)0.f;

    const unsigned short* Ag[4];
    const unsigned short* Bg[2];
#pragma unroll
    for (int q = 0; q < 4; q++)
        Ag[q] = wb + (size_t)(m0 + (w * 4 + q) * 16 + l15) * KC + quad * 8;
#pragma unroll
    for (int q = 0; q < 2; q++)
        Bg[q] = P + (size_t)(g * 64 + (w * 2 + q) * 16 + l15) * KC + quad * 8;

#pragma unroll 2
    for (int step = 0; step < KSTEPS; step++) {
        __syncthreads();
        int kof = step * 64;
#pragma unroll
        for (int kh = 0; kh < 2; kh++) {
#pragma unroll
            for (int q = 0; q < 4; q++)
                GLOAD_LDS16(Ag[q] + kof + kh * 32, &As[(kh * 8 + w * 4 + q) * 512]);
#pragma unroll
            for (int q = 0; q < 2; q++)
                GLOAD_LDS16(Bg[q] + kof + kh * 32, &Bs[(kh * 4 + w * 2 + q) * 512]);
        }
        __syncthreads();
#pragma unroll
        for (int kh = 0; kh < 2; kh++) {
            bf16x8 a[4], b[4];
#pragma unroll
            for (int i = 0; i < 4; i++)
                a[i] = *(const bf16x8*)&As[(kh * 8 + w * 4 + i) * 512 + lane * 8];
#pragma unroll
            for (int j = 0; j < 4; j++)
                b[j] = *(const bf16x8*)&Bs[(kh * 4 + j) * 512 + lane * 8];
#pragma unroll
            for (int i = 0; i < 4; i++)
#pragma unroll
                for (int j = 0; j < 4; j++)
                    acc[i][j] = __builtin_amdgcn_mfma_f32_16x16x32_bf16(a[i], b[j], acc[i][j], 0, 0, 0);
        }
    }

    if (t < 32) sgrp[t] = 0.f;
    __syncthreads();

    int b_ = ntile / HW;
    int p0 = ntile % HW;
#pragma unroll
    for (int i = 0; i < 4; i++) {
        float s = 0.f, ss = 0.f;
        int mbase = m0 + w * 64 + i * 16 + quad * 4;
#pragma unroll
        for (int j = 0; j < 4; j++) {
            float* ob = out + ((size_t)b_ * COUT + mbase) * HW + p0 + j * 16 + l15;
#pragma unroll
            for (int r = 0; r < 4; r++) {
                float v = acc[i][j][r];
                ob[(size_t)r * HW] = v;
                s  += v;
                ss += v * v;
            }
        }
        int gl = w * 8 + i * 2 + (quad >> 1);
        atomicAdd(&sgrp[gl],      s);
        atomicAdd(&sgrp[16 + gl], ss);
    }
    __syncthreads();
    if (t < 16) {
        int bg = b_ * 32 + mb * 16 + t;
        atomicAdd(&stats[bg * 2],     sgrp[t]);
        atomicAdd(&stats[bg * 2 + 1], sgrp[16 + t]);
    }
}

__global__ __launch_bounds__(256) void gn_norm(float* __restrict__ out,
                                               const float* __restrict__ stats,
                                               const float* __restrict__ gamma,
                                               const float* __restrict__ beta) {
    int i4 = blockIdx.x * 256 + threadIdx.x;
    if (i4 >= 1179648) return;
    float4 v = ((const float4*)out)[i4];
    int e  = i4 * 4;
    int ch = (e / HW) & 255;
    int b  = e / (HW * 256);
    int bg = b * 32 + (ch >> 3);
    float s = stats[bg * 2], ss = stats[bg * 2 + 1];
    float mean = s * (1.f / 73728.f);
    float rs   = rsqrtf(ss * (1.f / 73728.f) - mean * mean + 1e-5f);
    float ga = gamma[ch] * rs;
    float be = beta[ch] - mean * ga;
    v.x = fmaxf(v.x * ga + be, 0.f);
    v.y = fmaxf(v.y * ga + be, 0.f);
    v.z = fmaxf(v.z * ga + be, 0.f);
    v.w = fmaxf(v.w * ga + be, 0.f);
    ((float4*)out)[i4] = v;
}

extern "C" void kernel_launch(void* const* d_in, const int* in_sizes, int n_in,
                              void* d_out, int out_size, void* d_ws, size_t ws_size,
                              hipStream_t stream) {
    const float* x        = (const float*)d_in[0];
    const float* offset_w = (const float*)d_in[1];
    const float* offset_b = (const float*)d_in[2];
    const float* conv_w   = (const float*)d_in[3];
    const float* gamma    = (const float*)d_in[4];
    const float* beta     = (const float*)d_in[5];
    float* out = (float*)d_out;
    float* ws  = (float*)d_ws;

    float*          off   = ws;
    float*          stats = ws + 331776;
    unsigned short* wb    = (unsigned short*)(ws + 331904);
    float*          xt    = ws + 626816;
    unsigned short* P     = (unsigned short*)(ws + 5345408);

    const size_t baseB = 5345408ull * 4ull;
    int Nc;
    if      (ws_size >= baseB + (size_t)18432 * KC * 2) Nc = 18432;
    else if (ws_size >= baseB + (size_t)9216  * KC * 2) Nc = 9216;
    else if (ws_size >= baseB + (size_t)4608  * KC * 2) Nc = 4608;
    else                                                Nc = 2304;

    hipLaunchKernelGGL(prelude,     dim3(8208), dim3(256), 0, stream,
                       x, xt, conv_w, wb, offset_b, off, stats);
    hipLaunchKernelGGL(offset_conv, dim3(1152), dim3(256), 0, stream, x, offset_w, off);
    for (int n0 = 0; n0 < NTOT; n0 += Nc) {
        hipLaunchKernelGGL(gather3, dim3(9, Nc / 4), dim3(256), 0, stream, xt, off, P, n0);
        hipLaunchKernelGGL(gemm_mfma, dim3((Nc / 64) * 2), dim3(128), 0, stream,
                           wb, P, out, stats, n0, Nc / 64);
    }
    hipLaunchKernelGGL(gn_norm, dim3(4608), dim3(256), 0, stream, out, stats, gamma, beta);
}

// Round 7
// 258.258 us; speedup vs baseline: 1.1383x; 1.0293x over previous
//
#include <hip/hip_runtime.h>
#include <math.h>

#define HW 9216          // 96*96
#define WID 96
#define CIN 256
#define COUT 256
#define NTOT 18432       // B*HW
#define KC 2304          // CIN*9  (K of the implicit GEMM)

typedef short bf16x8 __attribute__((ext_vector_type(8)));
typedef float f32x4  __attribute__((ext_vector_type(4)));

#define GLOAD_LDS16(g, l)                                              \
    __builtin_amdgcn_global_load_lds(                                  \
        (const __attribute__((address_space(1))) void*)(g),            \
        (__attribute__((address_space(3))) void*)(l), 16, 0, 0)

__device__ __forceinline__ unsigned short f2bf(float f) {
    union { float f; unsigned int u; } v; v.f = f;
    unsigned int u = v.u;
    return (unsigned short)((u + 0x7fffu + ((u >> 16) & 1u)) >> 16);  // RNE
}

// ws layout (float offsets) — wb is 589824 ushorts = 294912 float slots:
//   off   : 0       .. 331776
//   stats : 331776  .. 331904
//   wb    : 331904  .. 626816   (256x2304 ushort, wb[oc][k*256+c])
//   xt    : 626816  .. 5345408  (NHWC fp32)
//   P     : 5345408 ..          (18432 x 2304 ushort)

// Prologue: [0,4608) xt transpose | [4608,6912) wb bf16 | [6912,8208) off init + stats=0
__global__ __launch_bounds__(256) void prelude(const float* __restrict__ x,
                                               float* __restrict__ xt,
                                               const float* __restrict__ cw,
                                               unsigned short* __restrict__ wb,
                                               const float* __restrict__ offset_b,
                                               float* __restrict__ off,
                                               float* __restrict__ stats) {
    __shared__ float L[32][33];
    int blk = blockIdx.x, t = threadIdx.x;
    if (blk < 4608) {                       // x NCHW -> NHWC
        int pt = blk % 288, ct = (blk / 288) & 7, b = blk / 2304;
        int pl = t & 31, ch = t >> 5;
#pragma unroll
        for (int i = 0; i < 4; i++) {
            int cl = ch * 4 + i;
            L[cl][pl] = x[((size_t)(b * CIN + ct * 32 + cl)) * HW + pt * 32 + pl];
        }
        __syncthreads();
        int cc = t & 31;
#pragma unroll
        for (int i = 0; i < 4; i++) {
            int pr = ch * 4 + i;
            xt[((size_t)(b * HW + pt * 32 + pr)) * 256 + ct * 32 + cc] = L[cc][pr];
        }
    } else if (blk < 6912) {                // conv_w -> wb bf16 [oc][k*256+c]
        int i = (blk - 4608) * 256 + t;
        int oc = i / KC, kc = i % KC;
        int k = kc >> 8, c = kc & 255;
        wb[i] = f2bf(cw[(oc * CIN + c) * 9 + k]);
    } else {                                // off = bias, stats = 0
        int i = (blk - 6912) * 256 + t;
        if (i < 331776) off[i] = offset_b[(i / HW) % 18];
        if (i < 128) stats[i] = 0.f;
    }
}

// 3x3 pad-1 conv -> 18 offset channels. 16 c-chunks x 72 = 1152 blocks.
__global__ __launch_bounds__(256) void offset_conv(const float* __restrict__ x,
                                                   const float* __restrict__ ow,
                                                   float* __restrict__ off) {
    int chunk = blockIdx.x / 72;
    int pg = (blockIdx.x % 72) * 256 + threadIdx.x;
    int b  = pg / HW;
    int p  = pg % HW;
    int ho = p / WID, wo = p % WID;
    const float* xb = x + (size_t)b * CIN * HW;

    float acc[18];
#pragma unroll
    for (int ch = 0; ch < 18; ch++) acc[ch] = 0.f;

    int c0 = chunk * 16;
    for (int ci = 0; ci < 16; ci++) {
        int c = c0 + ci;
        const float* xc = xb + (size_t)c * HW;
#pragma unroll
        for (int ky = 0; ky < 3; ky++) {
            int y = ho - 1 + ky;
            if (y < 0 || y >= 96) continue;
#pragma unroll
            for (int kx = 0; kx < 3; kx++) {
                int xx = wo - 1 + kx;
                float xv = (xx >= 0 && xx < 96) ? xc[y * WID + xx] : 0.f;
                int widx = c * 9 + ky * 3 + kx;
#pragma unroll
                for (int ch = 0; ch < 18; ch++)
                    acc[ch] += xv * ow[ch * (CIN * 9) + widx];
            }
        }
    }
#pragma unroll
    for (int ch = 0; ch < 18; ch++)
        atomicAdd(&off[((size_t)b * 18 + ch) * HW + p], acc[ch]);
}

// Gather v4: one wave per n, loop over the 9 kernel taps (ILP across taps).
// Lane handles 4 channels; 4 coalesced 1KB corner-row reads per tap.
__global__ __launch_bounds__(256) void gather4(const float* __restrict__ xt,
                                               const float* __restrict__ off,
                                               unsigned short* __restrict__ P) {
    int t    = threadIdx.x;
    int w    = t >> 6;
    int lane = t & 63;
    int n    = blockIdx.x * 4 + w;
    int b    = n / HW, p = n % HW;
    int ho   = p / WID, wo = p % WID;
    const float* xb = xt + (size_t)b * (HW * 256);
    const float* offb = off + (size_t)b * 18 * HW + p;
    int c4 = lane * 4;
    unsigned short* Pn = P + (size_t)n * KC + c4;

#pragma unroll 3
    for (int k = 0; k < 9; k++) {
        int ky = k / 3, kx = k % 3;
        float dy = offb[(size_t)(2 * k)     * HW];
        float dx = offb[(size_t)(2 * k + 1) * HW];
        float sy = (float)(ho - 1 + ky) + dy;
        float sx = (float)(wo - 1 + kx) + dx;
        float y0f = floorf(sy), x0f = floorf(sx);
        float fy = sy - y0f, fx = sx - x0f;
        int y0 = (int)y0f, x0 = (int)x0f;
        int y1 = y0 + 1, x1 = x0 + 1;
        float vy0 = (y0 >= 0 && y0 < 96) ? 1.f : 0.f;
        float vy1 = (y1 >= 0 && y1 < 96) ? 1.f : 0.f;
        float vx0 = (x0 >= 0 && x0 < 96) ? 1.f : 0.f;
        float vx1 = (x1 >= 0 && x1 < 96) ? 1.f : 0.f;
        int iy0 = min(max(y0, 0), 95) * WID, iy1 = min(max(y1, 0), 95) * WID;
        int ix0 = min(max(x0, 0), 95),       ix1 = min(max(x1, 0), 95);
        float w0 = (1.f - fy) * (1.f - fx) * vy0 * vx0;
        float w1 = (1.f - fy) * fx         * vy0 * vx1;
        float w2 = fy         * (1.f - fx) * vy1 * vx0;
        float w3 = fy         * fx         * vy1 * vx1;

        float4 v0 = *(const float4*)(xb + (size_t)(iy0 + ix0) * 256 + c4);
        float4 v1 = *(const float4*)(xb + (size_t)(iy0 + ix1) * 256 + c4);
        float4 v2 = *(const float4*)(xb + (size_t)(iy1 + ix0) * 256 + c4);
        float4 v3 = *(const float4*)(xb + (size_t)(iy1 + ix1) * 256 + c4);
        float r0 = w0 * v0.x + w1 * v1.x + w2 * v2.x + w3 * v3.x;
        float r1 = w0 * v0.y + w1 * v1.y + w2 * v2.y + w3 * v3.y;
        float r2 = w0 * v0.z + w1 * v1.z + w2 * v2.z + w3 * v3.z;
        float r3 = w0 * v0.w + w1 * v1.w + w2 * v2.w + w3 * v3.w;
        uint2 o;
        o.x = (unsigned)f2bf(r0) | ((unsigned)f2bf(r1) << 16);
        o.y = (unsigned)f2bf(r2) | ((unsigned)f2bf(r3) << 16);
        *((uint2*)(Pn + k * 256)) = o;
    }
}

// GEMM v4: block 256 thr (4 waves), tile 64M x 128N, wave 64M x 32N
// (4x2 16x16x32). BK=64, TRUE LDS double-buffer: after each barrier, issue
// next tile's global_load_lds into buf^1, then compute from buf — loads fly
// during the MFMA stretch. Fragment-order LDS (0 conflicts, R5-proven).
// Grid 576 flat; swizzle puts the 4 m-blocks of one B-tile 8 ids apart
// (same XCD slot, R5-proven). Plain stores + fused GN partial stats.
__global__ __launch_bounds__(256) void gemm_mfma(const unsigned short* __restrict__ wb,
                                                 const unsigned short* __restrict__ P,
                                                 float* __restrict__ out,
                                                 float* __restrict__ stats) {
    __shared__ __align__(16) unsigned short As[2][8 * 512];    // 16 KB
    __shared__ __align__(16) unsigned short Bs[2][16 * 512];   // 32 KB
    __shared__ float sgrp[16];
    int t    = threadIdx.x;
    int w    = t >> 6;
    int lane = t & 63;
    int l15  = lane & 15, quad = lane >> 4;

    int f  = blockIdx.x;
    int x_ = f & 7, s = f >> 3;
    int mb = s & 3;
    int g  = (s >> 2) * 8 + x_;       // n-tile [0,144)
    int m0 = mb * 64;

    f32x4 acc[4][2];
#pragma unroll
    for (int i = 0; i < 4; i++)
#pragma unroll
        for (int j = 0; j < 2; j++) acc[i][j] = (f32x4)0.f;

    // stage pointers: wave w stages a-frag w and b-frags {2w, 2w+1}
    const unsigned short* Ag  = wb + (size_t)(m0 + w * 16 + l15) * KC + quad * 8;
    const unsigned short* Bg0 = P  + (size_t)(g * 128 + (w * 2 + 0) * 16 + l15) * KC + quad * 8;
    const unsigned short* Bg1 = P  + (size_t)(g * 128 + (w * 2 + 1) * 16 + l15) * KC + quad * 8;

#define STAGE(bf, kc)                                                        \
    {                                                                        \
        _Pragma("unroll")                                                    \
        for (int kh = 0; kh < 2; kh++) {                                     \
            GLOAD_LDS16(Ag  + (kc) + kh * 32, &As[bf][(kh * 4 + w) * 512]);  \
            GLOAD_LDS16(Bg0 + (kc) + kh * 32, &Bs[bf][(kh * 8 + w * 2) * 512]); \
            GLOAD_LDS16(Bg1 + (kc) + kh * 32, &Bs[bf][(kh * 8 + w * 2 + 1) * 512]); \
        }                                                                    \
    }

    STAGE(0, 0);
    int cur = 0;
    for (int kc = 0; kc < KC; kc += 64) {
        __syncthreads();                       // drains buf[cur] writes; frees buf[cur^1]
        if (kc + 64 < KC) STAGE(cur ^ 1, kc + 64);
#pragma unroll
        for (int kh = 0; kh < 2; kh++) {
            bf16x8 a[4], b[2];
#pragma unroll
            for (int i = 0; i < 4; i++)
                a[i] = *(const bf16x8*)&As[cur][(kh * 4 + i) * 512 + lane * 8];
#pragma unroll
            for (int j = 0; j < 2; j++)
                b[j] = *(const bf16x8*)&Bs[cur][(kh * 8 + w * 2 + j) * 512 + lane * 8];
#pragma unroll
            for (int i = 0; i < 4; i++)
#pragma unroll
                for (int j = 0; j < 2; j++)
                    acc[i][j] = __builtin_amdgcn_mfma_f32_16x16x32_bf16(a[i], b[j], acc[i][j], 0, 0, 0);
        }
        cur ^= 1;
    }

    if (t < 16) sgrp[t] = 0.f;
    __syncthreads();

    int b_ = g / 72;
    int p0 = (g % 72) * 128 + w * 32;
#pragma unroll
    for (int i = 0; i < 4; i++) {
        float sv = 0.f, ssv = 0.f;
        int mr = m0 + i * 16 + quad * 4;
#pragma unroll
        for (int j = 0; j < 2; j++) {
            float* ob = out + ((size_t)b_ * COUT + mr) * HW + p0 + j * 16 + l15;
#pragma unroll
            for (int r = 0; r < 4; r++) {
                float v = acc[i][j][r];
                ob[(size_t)r * HW] = v;
                sv  += v;
                ssv += v * v;
            }
        }
        int gl = i * 2 + (quad >> 1);          // 8 GN groups in this 64-row m-block
        atomicAdd(&sgrp[gl],     sv);
        atomicAdd(&sgrp[8 + gl], ssv);
    }
    __syncthreads();
    if (t < 16) {
        int bg = b_ * 32 + mb * 8 + (t & 7);
        atomicAdd(&stats[bg * 2 + (t >> 3)], sgrp[t]);
    }
}

__global__ __launch_bounds__(256) void gn_norm(float* __restrict__ out,
                                               const float* __restrict__ stats,
                                               const float* __restrict__ gamma,
                                               const float* __restrict__ beta) {
    int i4 = blockIdx.x * 256 + threadIdx.x;
    if (i4 >= 1179648) return;
    float4 v = ((const float4*)out)[i4];
    int e  = i4 * 4;
    int ch = (e / HW) & 255;
    int b  = e / (HW * 256);
    int bg = b * 32 + (ch >> 3);
    float s = stats[bg * 2], ss = stats[bg * 2 + 1];
    float mean = s * (1.f / 73728.f);
    float rs   = rsqrtf(ss * (1.f / 73728.f) - mean * mean + 1e-5f);
    float ga = gamma[ch] * rs;
    float be = beta[ch] - mean * ga;
    v.x = fmaxf(v.x * ga + be, 0.f);
    v.y = fmaxf(v.y * ga + be, 0.f);
    v.z = fmaxf(v.z * ga + be, 0.f);
    v.w = fmaxf(v.w * ga + be, 0.f);
    ((float4*)out)[i4] = v;
}

extern "C" void kernel_launch(void* const* d_in, const int* in_sizes, int n_in,
                              void* d_out, int out_size, void* d_ws, size_t ws_size,
                              hipStream_t stream) {
    const float* x        = (const float*)d_in[0];
    const float* offset_w = (const float*)d_in[1];
    const float* offset_b = (const float*)d_in[2];
    const float* conv_w   = (const float*)d_in[3];
    const float* gamma    = (const float*)d_in[4];
    const float* beta     = (const float*)d_in[5];
    float* out = (float*)d_out;
    float* ws  = (float*)d_ws;

    float*          off   = ws;
    float*          stats = ws + 331776;
    unsigned short* wb    = (unsigned short*)(ws + 331904);
    float*          xt    = ws + 626816;
    unsigned short* P     = (unsigned short*)(ws + 5345408);

    hipLaunchKernelGGL(prelude,     dim3(8208), dim3(256), 0, stream,
                       x, xt, conv_w, wb, offset_b, off, stats);
    hipLaunchKernelGGL(offset_conv, dim3(1152), dim3(256), 0, stream, x, offset_w, off);
    hipLaunchKernelGGL(gather4,     dim3(4608), dim3(256), 0, stream, xt, off, P);
    hipLaunchKernelGGL(gemm_mfma,   dim3(576),  dim3(256), 0, stream, wb, P, out, stats);
    hipLaunchKernelGGL(gn_norm,     dim3(4608), dim3(256), 0, stream, out, stats, gamma, beta);
}

// Round 8
// 236.265 us; speedup vs baseline: 1.2443x; 1.0931x over previous
//
#include <hip/hip_runtime.h>
#include <math.h>

#define HW 9216          // 96*96
#define WID 96
#define CIN 256
#define COUT 256
#define NTOT 18432       // B*HW
#define KC 2304          // CIN*9
#define NKS 72           // KC/32 k-steps

typedef short bf16x8 __attribute__((ext_vector_type(8)));
typedef float f32x4  __attribute__((ext_vector_type(4)));

__device__ __forceinline__ unsigned short f2bf(float f) {
    union { float f; unsigned int u; } v; v.f = f;
    unsigned int u = v.u;
    return (unsigned short)((u + 0x7fffu + ((u >> 16) & 1u)) >> 16);  // RNE
}
__device__ __forceinline__ float bflo(unsigned u) {
    union { unsigned u; float f; } v; v.u = u << 16; return v.f;
}
__device__ __forceinline__ float bfhi(unsigned u) {
    union { unsigned u; float f; } v; v.u = u & 0xFFFF0000u; return v.f;
}

// ws layout (float offsets):
//   off  : 0       .. 331776
//   stats: 331776  .. 331904
//   A'   : 331904  .. 626816   (589824 ushort, fragment-major weights)
//   xt   : 626816  .. 2986112  (bf16 NHWC: [b][p][c], 4718592 ushort)
//   B'   : 2986112 ..          (42467328 ushort, fragment-major patches)
//
// Fragment-major layout (matches 16x16x32 MFMA operand order exactly):
//   A'[(((mb*72+ks)*4 + i)*64 + lane)*8 + s] = wbf16[m=mb*64+i*16+(lane&15)][ks*32+(lane>>4)*8+s]
//   B'[(((g *72+ks)*4 + j)*64 + lane)*8 + s] = P    [n=g *64+j*16+(lane&15)][ks*32+(lane>>4)*8+s]
// => a GEMM wave reads each fragment as ONE coalesced 1KB dwordx4 (base+lane*16).

// Prologue: [0,4608) xt transpose(bf16) | [4608,5184) A' swizzle | [5184,6480) off init + stats=0
__global__ __launch_bounds__(256) void prelude(const float* __restrict__ x,
                                               unsigned short* __restrict__ xt,
                                               const float* __restrict__ cw,
                                               unsigned short* __restrict__ Aw,
                                               const float* __restrict__ offset_b,
                                               float* __restrict__ off,
                                               float* __restrict__ stats) {
    __shared__ float L[32][33];
    int blk = blockIdx.x, t = threadIdx.x;
    if (blk < 4608) {                       // x NCHW fp32 -> NHWC bf16
        int pt = blk % 288, ct = (blk / 288) & 7, b = blk / 2304;
        int pl = t & 31, ch = t >> 5;
#pragma unroll
        for (int i = 0; i < 4; i++) {
            int cl = ch * 4 + i;
            L[cl][pl] = x[((size_t)(b * CIN + ct * 32 + cl)) * HW + pt * 32 + pl];
        }
        __syncthreads();
        int cc = t & 31;
#pragma unroll
        for (int i = 0; i < 4; i++) {
            int pr = ch * 4 + i;
            xt[((size_t)(b * HW + pt * 32 + pr)) * 256 + ct * 32 + cc] = f2bf(L[cc][pr]);
        }
    } else if (blk < 5184) {                // conv_w -> A' fragment-major bf16
        int tid = (blk - 4608) * 256 + t;   // [0,147456)
        int oc = tid / 576;
        int kc = (tid % 576) * 4;           // 4 consecutive kc
        int k = kc >> 8, c = kc & 255;
        unsigned short v[4] __attribute__((aligned(8)));
#pragma unroll
        for (int i = 0; i < 4; i++)
            v[i] = f2bf(cw[((size_t)oc * 256 + c + i) * 9 + k]);
        int ks = kc >> 5, quad = (kc >> 3) & 3, sidx = kc & 7;
        int ifr = (oc >> 4) & 3, lane = quad * 16 + (oc & 15);
        size_t flat = (((size_t)((oc >> 6) * 72 + ks) * 4 + ifr) * 64 + lane) * 8 + sidx;
        *(uint2*)(Aw + flat) = *(const uint2*)v;
    } else {                                // off = bias, stats = 0
        int i = (blk - 5184) * 256 + t;
        if (i < 331776) off[i] = offset_b[(i / HW) % 18];
        if (i < 128) stats[i] = 0.f;
    }
}

// 3x3 pad-1 conv -> 18 offset channels. 16 c-chunks x 72 = 1152 blocks.
__global__ __launch_bounds__(256) void offset_conv(const float* __restrict__ x,
                                                   const float* __restrict__ ow,
                                                   float* __restrict__ off) {
    int chunk = blockIdx.x / 72;
    int pg = (blockIdx.x % 72) * 256 + threadIdx.x;
    int b  = pg / HW;
    int p  = pg % HW;
    int ho = p / WID, wo = p % WID;
    const float* xb = x + (size_t)b * CIN * HW;

    float acc[18];
#pragma unroll
    for (int ch = 0; ch < 18; ch++) acc[ch] = 0.f;

    int c0 = chunk * 16;
    for (int ci = 0; ci < 16; ci++) {
        int c = c0 + ci;
        const float* xc = xb + (size_t)c * HW;
#pragma unroll
        for (int ky = 0; ky < 3; ky++) {
            int y = ho - 1 + ky;
            if (y < 0 || y >= 96) continue;
#pragma unroll
            for (int kx = 0; kx < 3; kx++) {
                int xx = wo - 1 + kx;
                float xv = (xx >= 0 && xx < 96) ? xc[y * WID + xx] : 0.f;
                int widx = c * 9 + ky * 3 + kx;
#pragma unroll
                for (int ch = 0; ch < 18; ch++)
                    acc[ch] += xv * ow[ch * (CIN * 9) + widx];
            }
        }
    }
#pragma unroll
    for (int ch = 0; ch < 18; ch++)
        atomicAdd(&off[((size_t)b * 18 + ch) * HW + p], acc[ch]);
}

// Gather: one wave per n, 9 taps; 4 coalesced 512B bf16 corner-row reads per
// tap; scatter-stores straight into B' fragment-major layout (8B per lane).
__global__ __launch_bounds__(256) void gather4(const unsigned short* __restrict__ xt,
                                               const float* __restrict__ off,
                                               unsigned short* __restrict__ Bp) {
    int t    = threadIdx.x;
    int w    = t >> 6;
    int lane = t & 63;
    int n    = blockIdx.x * 4 + w;
    int b    = n / HW, p = n % HW;
    int ho   = p / WID, wo = p % WID;
    const unsigned short* xb = xt + (size_t)b * (HW * 256);
    const float* offb = off + (size_t)b * 18 * HW + p;
    int c4 = lane * 4;

    int jfr = (n >> 4) & 3, l15n = n & 15;
    int lhi = lane >> 3, lq = (lane >> 1) & 3, lp = lane & 1;
    size_t gbase = (size_t)(n >> 6) * 72;

#pragma unroll 3
    for (int k = 0; k < 9; k++) {
        int ky = k / 3, kx = k % 3;
        float dy = offb[(size_t)(2 * k)     * HW];
        float dx = offb[(size_t)(2 * k + 1) * HW];
        float sy = (float)(ho - 1 + ky) + dy;
        float sx = (float)(wo - 1 + kx) + dx;
        float y0f = floorf(sy), x0f = floorf(sx);
        float fy = sy - y0f, fx = sx - x0f;
        int y0 = (int)y0f, x0 = (int)x0f;
        int y1 = y0 + 1, x1 = x0 + 1;
        float vy0 = (y0 >= 0 && y0 < 96) ? 1.f : 0.f;
        float vy1 = (y1 >= 0 && y1 < 96) ? 1.f : 0.f;
        float vx0 = (x0 >= 0 && x0 < 96) ? 1.f : 0.f;
        float vx1 = (x1 >= 0 && x1 < 96) ? 1.f : 0.f;
        int iy0 = min(max(y0, 0), 95) * WID, iy1 = min(max(y1, 0), 95) * WID;
        int ix0 = min(max(x0, 0), 95),       ix1 = min(max(x1, 0), 95);
        float w0 = (1.f - fy) * (1.f - fx) * vy0 * vx0;
        float w1 = (1.f - fy) * fx         * vy0 * vx1;
        float w2 = fy         * (1.f - fx) * vy1 * vx0;
        float w3 = fy         * fx         * vy1 * vx1;

        uint2 u0 = *(const uint2*)(xb + (size_t)(iy0 + ix0) * 256 + c4);
        uint2 u1 = *(const uint2*)(xb + (size_t)(iy0 + ix1) * 256 + c4);
        uint2 u2 = *(const uint2*)(xb + (size_t)(iy1 + ix0) * 256 + c4);
        uint2 u3 = *(const uint2*)(xb + (size_t)(iy1 + ix1) * 256 + c4);
        float r0 = w0 * bflo(u0.x) + w1 * bflo(u1.x) + w2 * bflo(u2.x) + w3 * bflo(u3.x);
        float r1 = w0 * bfhi(u0.x) + w1 * bfhi(u1.x) + w2 * bfhi(u2.x) + w3 * bfhi(u3.x);
        float r2 = w0 * bflo(u0.y) + w1 * bflo(u1.y) + w2 * bflo(u2.y) + w3 * bflo(u3.y);
        float r3 = w0 * bfhi(u0.y) + w1 * bfhi(u1.y) + w2 * bfhi(u2.y) + w3 * bfhi(u3.y);
        uint2 o;
        o.x = (unsigned)f2bf(r0) | ((unsigned)f2bf(r1) << 16);
        o.y = (unsigned)f2bf(r2) | ((unsigned)f2bf(r3) << 16);
        size_t ds = (((gbase + k * 8 + lhi) * 4 + jfr) * 64 + lq * 16 + l15n) * 8 + lp * 4;
        *(uint2*)(Bp + ds) = o;
    }
}

// Barrier-free register GEMM. Grid 1152 single-wave blocks (64 thr); wave
// tile 64M x 64N (4x4 16x16x32). Fragment-major A'/B' -> each k-step is
// 8 coalesced dwordx4 loads into VGPRs + 16 MFMA; unroll-by-3 register ring
// gives ~2-MFMA-block prefetch distance with per-wave vmcnt only (no LDS,
// no __syncthreads, no vmcnt(0) drains). XCD swizzle: the 4 m-waves of one
// B' tile are 8,16,24 ids apart (same XCD slot). Fused per-wave GN stats.
__global__ __launch_bounds__(64) void gemm_mfma(const unsigned short* __restrict__ Aw,
                                                const unsigned short* __restrict__ Bp,
                                                float* __restrict__ out,
                                                float* __restrict__ stats) {
    int lane = threadIdx.x;
    int l15 = lane & 15, quad = lane >> 4;
    int f = blockIdx.x;
    int low3 = f & 7, hi = f >> 3;
    int mb = hi & 3;
    int g  = low3 + (hi >> 2) * 8;        // [0,288)

    const bf16x8* Ab = (const bf16x8*)Aw + (size_t)mb * 72 * 4 * 64 + lane;
    const bf16x8* Bb = (const bf16x8*)Bp + (size_t)g  * 72 * 4 * 64 + lane;

    f32x4 acc[4][4];
#pragma unroll
    for (int i = 0; i < 4; i++)
#pragma unroll
        for (int j = 0; j < 4; j++) acc[i][j] = (f32x4)0.f;

    bf16x8 a0[4], b0[4], a1[4], b1[4], a2[4], b2[4];

#define LOADSET(aa, bb, ks)                                   \
    {                                                         \
        _Pragma("unroll")                                     \
        for (int q = 0; q < 4; q++) {                         \
            aa[q] = Ab[((ks) * 4 + q) * 64];                  \
            bb[q] = Bb[((ks) * 4 + q) * 64];                  \
        }                                                     \
    }
#define MFMASET(aa, bb)                                                       \
    {                                                                         \
        _Pragma("unroll")                                                     \
        for (int i = 0; i < 4; i++)                                           \
            _Pragma("unroll")                                                 \
            for (int j = 0; j < 4; j++)                                       \
                acc[i][j] = __builtin_amdgcn_mfma_f32_16x16x32_bf16(          \
                    aa[i], bb[j], acc[i][j], 0, 0, 0);                        \
    }

    LOADSET(a0, b0, 0);
    LOADSET(a1, b1, 1);
    LOADSET(a2, b2, 2);
    for (int ks = 0; ks < 67; ks += 3) {
        MFMASET(a0, b0); LOADSET(a0, b0, ks + 3);
        MFMASET(a1, b1); LOADSET(a1, b1, ks + 4);
        MFMASET(a2, b2); LOADSET(a2, b2, ks + 5);
    }
    MFMASET(a0, b0);    // ks 69
    MFMASET(a1, b1);    // ks 70
    MFMASET(a2, b2);    // ks 71

    int b_ = g / 144;
    int p0 = (g % 144) * 64;
    float s[4] = {0.f, 0.f, 0.f, 0.f}, ss[4] = {0.f, 0.f, 0.f, 0.f};
#pragma unroll
    for (int i = 0; i < 4; i++) {
        int mr = mb * 64 + i * 16 + quad * 4;
#pragma unroll
        for (int j = 0; j < 4; j++) {
            float* ob = out + ((size_t)b_ * COUT + mr) * HW + p0 + j * 16 + l15;
#pragma unroll
            for (int r = 0; r < 4; r++) {
                float v = acc[i][j][r];
                ob[(size_t)r * HW] = v;
                s[i]  += v;
                ss[i] += v * v;
            }
        }
    }
#pragma unroll
    for (int i = 0; i < 4; i++) {
        float sv = s[i], ssv = ss[i];
#pragma unroll
        for (int d = 1; d < 32; d <<= 1) {
            sv  += __shfl_xor(sv,  d);
            ssv += __shfl_xor(ssv, d);
        }
        if ((lane & 31) == 0) {
            int bg = b_ * 32 + mb * 8 + i * 2 + (lane >> 5);
            atomicAdd(&stats[bg * 2],     sv);
            atomicAdd(&stats[bg * 2 + 1], ssv);
        }
    }
}

__global__ __launch_bounds__(256) void gn_norm(float* __restrict__ out,
                                               const float* __restrict__ stats,
                                               const float* __restrict__ gamma,
                                               const float* __restrict__ beta) {
    int i4 = blockIdx.x * 256 + threadIdx.x;
    if (i4 >= 1179648) return;
    float4 v = ((const float4*)out)[i4];
    int e  = i4 * 4;
    int ch = (e / HW) & 255;
    int b  = e / (HW * 256);
    int bg = b * 32 + (ch >> 3);
    float s = stats[bg * 2], ss = stats[bg * 2 + 1];
    float mean = s * (1.f / 73728.f);
    float rs   = rsqrtf(ss * (1.f / 73728.f) - mean * mean + 1e-5f);
    float ga = gamma[ch] * rs;
    float be = beta[ch] - mean * ga;
    v.x = fmaxf(v.x * ga + be, 0.f);
    v.y = fmaxf(v.y * ga + be, 0.f);
    v.z = fmaxf(v.z * ga + be, 0.f);
    v.w = fmaxf(v.w * ga + be, 0.f);
    ((float4*)out)[i4] = v;
}

extern "C" void kernel_launch(void* const* d_in, const int* in_sizes, int n_in,
                              void* d_out, int out_size, void* d_ws, size_t ws_size,
                              hipStream_t stream) {
    const float* x        = (const float*)d_in[0];
    const float* offset_w = (const float*)d_in[1];
    const float* offset_b = (const float*)d_in[2];
    const float* conv_w   = (const float*)d_in[3];
    const float* gamma    = (const float*)d_in[4];
    const float* beta     = (const float*)d_in[5];
    float* out = (float*)d_out;
    float* ws  = (float*)d_ws;

    float*          off   = ws;
    float*          stats = ws + 331776;
    unsigned short* Aw    = (unsigned short*)(ws + 331904);
    unsigned short* xt    = (unsigned short*)(ws + 626816);
    unsigned short* Bp    = (unsigned short*)(ws + 2986112);

    hipLaunchKernelGGL(prelude,     dim3(6480), dim3(256), 0, stream,
                       x, xt, conv_w, Aw, offset_b, off, stats);
    hipLaunchKernelGGL(offset_conv, dim3(1152), dim3(256), 0, stream, x, offset_w, off);
    hipLaunchKernelGGL(gather4,     dim3(4608), dim3(256), 0, stream, xt, off, Bp);
    hipLaunchKernelGGL(gemm_mfma,   dim3(1152), dim3(64),  0, stream, Aw, Bp, out, stats);
    hipLaunchKernelGGL(gn_norm,     dim3(4608), dim3(256), 0, stream, out, stats, gamma, beta);
}